// Round 3
// baseline (105.016 us; speedup 1.0000x reference)
//
#include <hip/hip_runtime.h>

#define IN_F     512
#define OUT_F    10240
#define NPROJ    6
#define THREADS  512
#define PER_T    (OUT_F / THREADS)   // 20 outputs per thread
#define ROWS     4                   // batch rows per block
#define NBINS    256
#define MAXLVL   5
#define CAND_CAP 64

typedef float float4v __attribute__((ext_vector_type(4)));

// Exact top-k threshold select + store for one of the 4 rows.
// acc[i][RR] holds activation of output (t + i*THREADS) for batch row b0+RR.
template<int RR>
__device__ __forceinline__ void select_and_store(
    const float4v* __restrict__ acc, int t, int lane, int wave,
    int b0, int batch, const int* __restrict__ hlen, float* __restrict__ out,
    unsigned* s_hist, float* s_wmax, unsigned* s_wsum, unsigned* s_bc,
    float* s_cand, unsigned* s_ccount, float* s_kth)
{
    auto comp = [](float4v v) -> float {
        if constexpr (RR == 0) return v.x;
        else if constexpr (RR == 1) return v.y;
        else if constexpr (RR == 2) return v.z;
        else return v.w;
    };

    // --- block max (activations are >= 0) ---
    float m = 0.0f;
#pragma unroll
    for (int i = 0; i < PER_T; ++i) m = fmaxf(m, comp(acc[i]));
#pragma unroll
    for (int d = 1; d < 64; d <<= 1) m = fmaxf(m, __shfl_xor(m, d));
    if (lane == 0) s_wmax[wave] = m;
    __syncthreads();
    float M = s_wmax[0];
#pragma unroll
    for (int w = 1; w < THREADS / 64; ++w) M = fmaxf(M, s_wmax[w]);

    float kth = 0.0f;
    if (M > 0.0f) {
        int need = hlen[0];                       // rank from the top (k)
        unsigned alive = (PER_T >= 32) ? 0xFFFFFFFFu : ((1u << PER_T) - 1u);
        float r[PER_T];                           // monotone residual keys
        const float scale0 = 255.0f / M;
#pragma unroll
        for (int i = 0; i < PER_T; ++i) r[i] = comp(acc[i]) * scale0;

        unsigned cnt_in_bin = 0;
        for (int level = 0; level < MAXLVL; ++level) {
            if (t < NBINS) s_hist[t] = 0u;
            __syncthreads();

            // histogram alive values; linear bins -> atomics spread by density
#pragma unroll
            for (int i = 0; i < PER_T; ++i) {
                if (alive & (1u << i)) {
                    int bin = (int)r[i];
                    bin = (bin > NBINS - 1) ? (NBINS - 1) : bin;
                    atomicAdd(&s_hist[bin], 1u);
                }
            }
            __syncthreads();

            // parallel suffix scan over bins (threads 0..255, waves 0..3)
            const unsigned h = (t < NBINS) ? s_hist[t] : 0u;
            unsigned s = h;
#pragma unroll
            for (int d = 1; d < 64; d <<= 1) {
                const unsigned o = __shfl_down(s, d);
                if (lane + d < 64) s += o;
            }
            if (wave < 4 && lane == 0) s_wsum[wave] = s;
            __syncthreads();
            for (int w = wave + 1; w < 4; ++w) s += s_wsum[w];
            const int S = (int)s;

            // unique bin containing the need-th largest
            if (h > 0u && S >= need && (S - (int)h) < need) {
                s_bc[0] = (unsigned)t;            // bin B
                s_bc[1] = (unsigned)(S - (int)h); // count strictly above bin B
                s_bc[2] = h;                      // count inside bin B
            }
            __syncthreads();
            const int B = (int)s_bc[0];
            need      -= (int)s_bc[1];
            cnt_in_bin = s_bc[2];

            // narrow alive set to bin B; refine residual keys (monotone)
#pragma unroll
            for (int i = 0; i < PER_T; ++i) {
                if (alive & (1u << i)) {
                    int bin = (int)r[i];
                    bin = (bin > NBINS - 1) ? (NBINS - 1) : bin;
                    if (bin != B) alive &= ~(1u << i);
                    else          r[i] = (r[i] - (float)B) * 256.0f;
                }
            }
            if (cnt_in_bin <= CAND_CAP) break;
        }

        // --- exact rank select over the candidates ---
        if (t == 0) *s_ccount = 0u;
        __syncthreads();
#pragma unroll
        for (int i = 0; i < PER_T; ++i) {
            if (alive & (1u << i)) {
                const unsigned idx = atomicAdd(s_ccount, 1u);
                if (idx < CAND_CAP) s_cand[idx] = comp(acc[i]);
            }
        }
        __syncthreads();
        const unsigned c = *s_ccount;
        if (c > CAND_CAP) {
            // >64 values within a sub-ulp span: all bit-identical
            if (t == 0) *s_kth = s_cand[0];
        } else if (t < (int)c) {
            const float v = s_cand[t];
            int gt = 0, eq = 0;
            for (unsigned j = 0; j < c; ++j) {
                const float u = s_cand[j];
                gt += (u > v);
                eq += (u == v);
            }
            if (gt < need && gt + eq >= need) *s_kth = v;  // ties write same value
        }
        __syncthreads();
        kth = *s_kth;
    }

    // --- predicated coalesced store ---
    const int br = b0 + RR;
    if (br < batch) {
        float* orow = out + (size_t)br * OUT_F;
#pragma unroll
        for (int i = 0; i < PER_T; ++i) {
            const int o = t + i * THREADS;
            const float v = comp(acc[i]);
            orow[o] = (v >= kth) ? v : 0.0f;
        }
    }
    __syncthreads();
}

__global__ __launch_bounds__(THREADS) void flyhash_wta_kernel(
    const float* __restrict__ inp,
    const int*   __restrict__ proj,
    const int*   __restrict__ hlen,
    float*       __restrict__ out,
    int batch)
{
    __shared__ float4v  s_rowT[IN_F];     // [feature] -> rows b0..b0+3 (8 KB)
    __shared__ unsigned s_hist[NBINS];
    __shared__ float    s_wmax[THREADS / 64];
    __shared__ unsigned s_wsum[4];
    __shared__ unsigned s_bc[3];
    __shared__ float    s_cand[CAND_CAP];
    __shared__ unsigned s_ccount;
    __shared__ float    s_kth;

    const int t    = threadIdx.x;
    const int lane = t & 63;
    const int wave = t >> 6;
    const int b0   = blockIdx.x * ROWS;

    // --- stage 4 rows, feature-major transposed; LDS writes are linear
    //     (addr_dw = c*4 + r = t + p*2048/4) -> conflict-free ---
    {
        const int r     = t & 3;
        const int cbase = t >> 2;
        int br = b0 + r;
        if (br >= batch) br = batch - 1;       // clamp (reads only)
        const float* grow = inp + (size_t)br * IN_F;
#pragma unroll
        for (int p = 0; p < 4; ++p) {
            const int c = cbase + p * (THREADS / 4);
            ((float*)s_rowT)[c * 4 + r] = grow[c];
        }
    }
    __syncthreads();

    // --- gather: one ds_read_b128 per index serves all 4 rows ---
    float4v acc[PER_T];
#pragma unroll
    for (int i = 0; i < PER_T; ++i) {
        const int o = t + i * THREADS;
        const int2* ip = (const int2*)(proj + (size_t)o * NPROJ);
        const int2 p0 = ip[0];
        const int2 p1 = ip[1];
        const int2 p2 = ip[2];
        // same per-component summation order as rounds 1-2 (absmax 0)
        const float4v a01 = s_rowT[p0.x] + s_rowT[p0.y];
        const float4v a23 = s_rowT[p1.x] + s_rowT[p1.y];
        const float4v a45 = s_rowT[p2.x] + s_rowT[p2.y];
        acc[i] = (a01 + a23) + a45;
    }
    __syncthreads();

    select_and_store<0>(acc, t, lane, wave, b0, batch, hlen, out,
                        s_hist, s_wmax, s_wsum, s_bc, s_cand, &s_ccount, &s_kth);
    select_and_store<1>(acc, t, lane, wave, b0, batch, hlen, out,
                        s_hist, s_wmax, s_wsum, s_bc, s_cand, &s_ccount, &s_kth);
    select_and_store<2>(acc, t, lane, wave, b0, batch, hlen, out,
                        s_hist, s_wmax, s_wsum, s_bc, s_cand, &s_ccount, &s_kth);
    select_and_store<3>(acc, t, lane, wave, b0, batch, hlen, out,
                        s_hist, s_wmax, s_wsum, s_bc, s_cand, &s_ccount, &s_kth);
}

extern "C" void kernel_launch(void* const* d_in, const int* in_sizes, int n_in,
                              void* d_out, int out_size, void* d_ws, size_t ws_size,
                              hipStream_t stream) {
    const float* inp  = (const float*)d_in[0];
    const int*   proj = (const int*)d_in[1];
    const int*   hlen = (const int*)d_in[2];
    float*       out  = (float*)d_out;

    const int batch  = in_sizes[0] / IN_F;            // 4096
    const int blocks = (batch + ROWS - 1) / ROWS;     // 1024

    hipLaunchKernelGGL(flyhash_wta_kernel, dim3(blocks), dim3(THREADS), 0, stream,
                       inp, proj, hlen, out, batch);
}

// Round 4
// 66.387 us; speedup vs baseline: 1.5819x; 1.5819x over previous
//
#include <hip/hip_runtime.h>

#define IN_F     512
#define OUT_F    10240
#define NPROJ    6
#define THREADS  512
#define PER_T    (OUT_F / THREADS)   // 20 outputs per thread
#define ROWS     4                   // batch rows per block
#define NBINS    256
#define MAXLVL   4
#define CAND_CAP 64

typedef float    float4v __attribute__((ext_vector_type(4)));
typedef unsigned uint4v  __attribute__((ext_vector_type(4)));

// One block = 4 batch rows.
//  - stage 4 rows feature-major (transposed) in LDS; gather via ds_read_b128
//    (one read serves all 4 rows)
//  - ALL 4 top-k selections run in lockstep in one pass: 4 histograms built
//    concurrently, 4 suffix scans by waves 0..3 concurrently, joint refine.
//  - exact rank select over <=64 candidates per row (original values).
__global__ __launch_bounds__(THREADS, 4) void flyhash_wta_kernel(
    const float* __restrict__ inp,
    const int*   __restrict__ proj,
    const int*   __restrict__ hlen,
    float*       __restrict__ out,
    int batch)
{
    __shared__ float4v             s_rowT[IN_F];          // 8 KB
    __shared__ __align__(16) unsigned s_hist4[ROWS][NBINS]; // 4 KB
    __shared__ float4v             s_wmax4[THREADS / 64];
    __shared__ unsigned            s_bc4[ROWS][3];        // {B, above, cnt}
    __shared__ float               s_cand4[ROWS][CAND_CAP];
    __shared__ unsigned            s_ccount4[ROWS];
    __shared__ float               s_kth4[ROWS];

    const int t    = threadIdx.x;
    const int lane = t & 63;
    const int wave = t >> 6;
    const int b0   = blockIdx.x * ROWS;

    // --- stage 4 rows transposed; LDS writes linear (addr_dw = c*4+r = t + p*512) ---
    {
        const int r     = t & 3;
        const int cbase = t >> 2;
        int br = b0 + r;
        if (br >= batch) br = batch - 1;
        const float* grow = inp + (size_t)br * IN_F;
#pragma unroll
        for (int p = 0; p < 4; ++p) {
            const int c = cbase + p * (THREADS / 4);
            ((float*)s_rowT)[c * 4 + r] = grow[c];
        }
    }
    __syncthreads();

    // --- gather: one ds_read_b128 per index serves all 4 rows ---
    float4v acc[PER_T];
#pragma unroll
    for (int i = 0; i < PER_T; ++i) {
        const int o = t + i * THREADS;
        const int2* ip = (const int2*)(proj + (size_t)o * NPROJ);
        const int2 p0 = ip[0];
        const int2 p1 = ip[1];
        const int2 p2 = ip[2];
        // same per-component summation order as rounds 1-3 (absmax 0)
        const float4v a01 = s_rowT[p0.x] + s_rowT[p0.y];
        const float4v a23 = s_rowT[p1.x] + s_rowT[p1.y];
        const float4v a45 = s_rowT[p2.x] + s_rowT[p2.y];
        acc[i] = (a01 + a23) + a45;
    }

    // --- per-row max (activations >= 0) ---
    float4v m4 = acc[0];
#pragma unroll
    for (int i = 1; i < PER_T; ++i) {
        m4.x = fmaxf(m4.x, acc[i].x);
        m4.y = fmaxf(m4.y, acc[i].y);
        m4.z = fmaxf(m4.z, acc[i].z);
        m4.w = fmaxf(m4.w, acc[i].w);
    }
#pragma unroll
    for (int d = 1; d < 64; d <<= 1) {
        m4.x = fmaxf(m4.x, __shfl_xor(m4.x, d));
        m4.y = fmaxf(m4.y, __shfl_xor(m4.y, d));
        m4.z = fmaxf(m4.z, __shfl_xor(m4.z, d));
        m4.w = fmaxf(m4.w, __shfl_xor(m4.w, d));
    }
    if (lane == 0) s_wmax4[wave] = m4;
    __syncthreads();
    float4v M4 = s_wmax4[0];
#pragma unroll
    for (int w = 1; w < THREADS / 64; ++w) {
        M4.x = fmaxf(M4.x, s_wmax4[w].x);
        M4.y = fmaxf(M4.y, s_wmax4[w].y);
        M4.z = fmaxf(M4.z, s_wmax4[w].z);
        M4.w = fmaxf(M4.w, s_wmax4[w].w);
    }

    // --- per-row selection state (all loops unrolled -> static indices) ---
    const int k0 = hlen[0];
    int      need[ROWS];
    float    scl[ROWS], off[ROWS];
    unsigned alive[ROWS];
    unsigned rowvalid = 0;
#pragma unroll
    for (int r = 0; r < ROWS; ++r) {
        need[r]  = k0;
        off[r]   = 0.0f;
        alive[r] = (1u << PER_T) - 1u;
        const float Mr = M4[r];
        scl[r] = (Mr > 0.0f) ? 255.0f / Mr : 0.0f;
        if (Mr > 0.0f) rowvalid |= (1u << r);
    }
    unsigned rowactive = rowvalid;

    // --- joint refinement loop (typically exits after level 0) ---
    for (int level = 0; level < MAXLVL && rowactive; ++level) {
        ((unsigned*)s_hist4)[t]           = 0u;
        ((unsigned*)s_hist4)[t + THREADS] = 0u;
        __syncthreads();

        // histogram all active rows in one pass
#pragma unroll
        for (int r = 0; r < ROWS; ++r) {
            if (rowactive & (1u << r)) {
#pragma unroll
                for (int i = 0; i < PER_T; ++i) {
                    if (alive[r] & (1u << i)) {
                        const float key = acc[i][r] * scl[r] - off[r];
                        int bin = (int)key;
                        bin = bin < 0 ? 0 : (bin > NBINS - 1 ? NBINS - 1 : bin);
                        atomicAdd(&s_hist4[r][bin], 1u);
                    }
                }
            }
        }
        __syncthreads();

        // 4 concurrent suffix scans: wave r handles row r (lane holds 4 bins)
        if (wave < ROWS && (rowactive & (1u << wave))) {
            const uint4v h = ((const uint4v*)&s_hist4[wave][0])[lane];
            const unsigned s3 = h.w;
            const unsigned s2 = h.z + s3;
            const unsigned s1 = h.y + s2;
            const unsigned s0 = h.x + s1;          // quad total
            unsigned T = s0;
#pragma unroll
            for (int d = 1; d < 64; d <<= 1) {
                const unsigned o = __shfl_down(T, d);
                if (lane + d < 64) T += o;
            }
            const unsigned A = T - s0;             // sum over lanes > lane
            const int nd = (wave == 0) ? need[0] : (wave == 1) ? need[1]
                         : (wave == 2) ? need[2] : need[3];
            const unsigned S0 = A + s0, S1 = A + s1, S2 = A + s2, S3 = A + s3;
            if (h.x && (int)S0 >= nd && (int)(S0 - h.x) < nd) {
                s_bc4[wave][0] = 4u * lane + 0u; s_bc4[wave][1] = S0 - h.x; s_bc4[wave][2] = h.x;
            }
            if (h.y && (int)S1 >= nd && (int)(S1 - h.y) < nd) {
                s_bc4[wave][0] = 4u * lane + 1u; s_bc4[wave][1] = S1 - h.y; s_bc4[wave][2] = h.y;
            }
            if (h.z && (int)S2 >= nd && (int)(S2 - h.z) < nd) {
                s_bc4[wave][0] = 4u * lane + 2u; s_bc4[wave][1] = S2 - h.z; s_bc4[wave][2] = h.z;
            }
            if (h.w && (int)S3 >= nd && (int)(S3 - h.w) < nd) {
                s_bc4[wave][0] = 4u * lane + 3u; s_bc4[wave][1] = S3 - h.w; s_bc4[wave][2] = h.w;
            }
        }
        __syncthreads();

        // joint refine: narrow alive sets, update per-row transforms
#pragma unroll
        for (int r = 0; r < ROWS; ++r) {
            if (rowactive & (1u << r)) {
                const int      B = (int)s_bc4[r][0];
                const int  above = (int)s_bc4[r][1];
                const unsigned c = s_bc4[r][2];
                need[r] -= above;
#pragma unroll
                for (int i = 0; i < PER_T; ++i) {
                    if (alive[r] & (1u << i)) {
                        const float key = acc[i][r] * scl[r] - off[r];
                        int bin = (int)key;
                        bin = bin < 0 ? 0 : (bin > NBINS - 1 ? NBINS - 1 : bin);
                        if (bin != B) alive[r] &= ~(1u << i);
                    }
                }
                off[r] = (off[r] + (float)B) * 256.0f;
                scl[r] *= 256.0f;
                if (c <= CAND_CAP) rowactive &= ~(1u << r);
            }
        }
    }

    // --- candidates + exact rank select (original values -> exact ties) ---
    if (t < ROWS) { s_ccount4[t] = 0u; s_kth4[t] = 0.0f; }
    __syncthreads();
#pragma unroll
    for (int r = 0; r < ROWS; ++r) {
        if (rowvalid & (1u << r)) {
#pragma unroll
            for (int i = 0; i < PER_T; ++i) {
                if (alive[r] & (1u << i)) {
                    const unsigned idx = atomicAdd(&s_ccount4[r], 1u);
                    if (idx < CAND_CAP) s_cand4[r][idx] = acc[i][r];
                }
            }
        }
    }
    __syncthreads();
    if (wave < ROWS && (rowvalid & (1u << wave))) {
        const unsigned c = s_ccount4[wave];
        const int nd = (wave == 0) ? need[0] : (wave == 1) ? need[1]
                     : (wave == 2) ? need[2] : need[3];
        if (c > CAND_CAP) {
            // values within a sub-ulp span after refinement: treat as ties
            if (lane == 0) s_kth4[wave] = s_cand4[wave][0];
        } else if (lane < (int)c) {
            const float v = s_cand4[wave][lane];
            int gt = 0, eq = 0;
            for (unsigned j = 0; j < c; ++j) {
                const float u = s_cand4[wave][j];
                gt += (u > v);
                eq += (u == v);
            }
            if (gt < nd && gt + eq >= nd) s_kth4[wave] = v;  // ties write same value
        }
    }
    __syncthreads();
    const float4v kth4 = { s_kth4[0], s_kth4[1], s_kth4[2], s_kth4[3] };

    // --- predicated coalesced stores ---
#pragma unroll
    for (int r = 0; r < ROWS; ++r) {
        const int br = b0 + r;
        if (br < batch) {
            float* orow = out + (size_t)br * OUT_F;
#pragma unroll
            for (int i = 0; i < PER_T; ++i) {
                const float v = acc[i][r];
                orow[t + i * THREADS] = (v >= kth4[r]) ? v : 0.0f;
            }
        }
    }
}

extern "C" void kernel_launch(void* const* d_in, const int* in_sizes, int n_in,
                              void* d_out, int out_size, void* d_ws, size_t ws_size,
                              hipStream_t stream) {
    const float* inp  = (const float*)d_in[0];
    const int*   proj = (const int*)d_in[1];
    const int*   hlen = (const int*)d_in[2];
    float*       out  = (float*)d_out;

    const int batch  = in_sizes[0] / IN_F;            // 4096
    const int blocks = (batch + ROWS - 1) / ROWS;     // 1024

    hipLaunchKernelGGL(flyhash_wta_kernel, dim3(blocks), dim3(THREADS), 0, stream,
                       inp, proj, hlen, out, batch);
}